// Round 1
// baseline (720.190 us; speedup 1.0000x reference)
//
#include <hip/hip_runtime.h>

// Problem constants (fixed by setup_inputs)
#define T_TABLES 4
#define B_BATCH  4096
#define D_DIM    64
#define C_SETS   100003
#define W_WAYS   4
#define A_AUX    4096
#define N_ROWS   500000
#define CW_LIM   (W_WAYS * C_SETS)          // 400012 : rows below this are the set-assoc region
#define N_CACHE_ROWS (CW_LIM + A_AUX)       // 404108

// Kernel 1: per-table hit/way detection + miss-rank prefix sum -> cache_lookup.
// One block per table, 1024 threads, each thread handles 4 consecutive positions
// (preserves the sequential cumsum order: thread tid covers b = 4*tid .. 4*tid+3).
__global__ __launch_bounds__(1024) void lookup_kernel(
    const int* __restrict__ lS_i,       // [T, B]
    const int* __restrict__ occ,        // [T, C, W] (W=4 -> int4 aligned)
    float* __restrict__ out_lookup_f,   // [T, B] written as float values
    int*   __restrict__ ws_lookup)      // [T, B] int scratch for kernel 2
{
    const int t    = blockIdx.x;
    const int tid  = threadIdx.x;
    const int lane = tid & 63;
    const int wv   = tid >> 6;          // 16 waves

    const int4* idx4p = (const int4*)(lS_i + t * B_BATCH);
    const int4* occ4  = (const int4*)occ;   // element i = occ[t*C + s], 16B each

    int4 idx4 = idx4p[tid];
    int idxs[4] = {idx4.x, idx4.y, idx4.z, idx4.w};

    int lks[4];     // hit lookup (valid when missf==0)
    int missf[4];
    int pre[4];     // misses among this thread's earlier k
    int m = 0;
    #pragma unroll
    for (int k = 0; k < 4; ++k) {
        int idx = idxs[k];
        unsigned s = (unsigned)idx % (unsigned)C_SETS;
        int4 r = occ4[(size_t)t * C_SETS + s];
        int way = -1;
        if      (r.x == idx) way = 0;
        else if (r.y == idx) way = 1;
        else if (r.z == idx) way = 2;
        else if (r.w == idx) way = 3;
        pre[k] = m;
        if (way >= 0) { lks[k] = way * C_SETS + (int)s; missf[k] = 0; }
        else          { lks[k] = 0;                     missf[k] = 1; m++; }
    }

    // inclusive wave scan of per-thread miss counts
    int v = m;
    #pragma unroll
    for (int d = 1; d < 64; d <<= 1) {
        int n = __shfl_up(v, d, 64);
        if (lane >= d) v += n;
    }

    __shared__ int wsums[16];
    if (lane == 63) wsums[wv] = v;
    __syncthreads();
    if (tid == 0) {                      // exclusive scan of 16 wave totals
        int run = 0;
        #pragma unroll
        for (int w = 0; w < 16; ++w) { int x = wsums[w]; wsums[w] = run; run += x; }
    }
    __syncthreads();

    const int base = wsums[wv] + (v - m);   // exclusive miss count before this thread

    #pragma unroll
    for (int k = 0; k < 4; ++k) {
        int lk = missf[k] ? (CW_LIM + base + pre[k]) : lks[k];
        int p  = t * B_BATCH + tid * 4 + k;
        out_lookup_f[p] = (float)lk;        // output 1, float-encoded
        ws_lookup[p]    = lk;               // for gather kernel
    }
}

// Kernel 2: gather + bag pooling. One wave per bag (lane = embedding dim),
// 4 bags per 256-thread block. Hits read cache_weights; misses read the full
// table directly (the reference's aux-scatter then gather is identity).
__global__ __launch_bounds__(256) void gather_kernel(
    const int*   __restrict__ lS_o,      // [T, B]
    const int*   __restrict__ lS_i,      // [T, B]
    const int*   __restrict__ ws_lookup, // [T, B]
    const float* __restrict__ cw,        // [T, N_CACHE_ROWS, D]
    const float* __restrict__ ft,        // [T, N_ROWS, D]
    float* __restrict__ out_pooled)      // [T, B, D]
{
    const int g    = blockIdx.x * 4 + (threadIdx.x >> 6);  // global bag id
    const int lane = threadIdx.x & 63;
    const int t    = g >> 12;            // / B_BATCH
    const int b    = g & (B_BATCH - 1);

    const int* offs = lS_o + t * B_BATCH;
    const int start = offs[b];
    const int end   = (b == B_BATCH - 1) ? B_BATCH : offs[b + 1];

    float acc = 0.f;
    for (int i = start; i < end; ++i) {
        const int p  = t * B_BATCH + i;
        const int lk = ws_lookup[p];
        const float* src = (lk < CW_LIM)
            ? (cw + ((size_t)t * N_CACHE_ROWS + (size_t)lk) * D_DIM)
            : (ft + ((size_t)t * N_ROWS + (size_t)lS_i[p]) * D_DIM);
        acc += src[lane];
    }
    out_pooled[(size_t)g * D_DIM + lane] = acc;
}

extern "C" void kernel_launch(void* const* d_in, const int* in_sizes, int n_in,
                              void* d_out, int out_size, void* d_ws, size_t ws_size,
                              hipStream_t stream) {
    const int*   lS_o = (const int*)d_in[0];
    const int*   lS_i = (const int*)d_in[1];
    const int*   occ  = (const int*)d_in[2];
    const float* cw   = (const float*)d_in[3];
    const float* ft   = (const float*)d_in[4];

    float* out_pooled   = (float*)d_out;                               // [T,B,D]
    float* out_lookup_f = out_pooled + (size_t)T_TABLES * B_BATCH * D_DIM; // [T,B]
    int*   ws_lookup    = (int*)d_ws;                                  // [T,B]

    lookup_kernel<<<T_TABLES, 1024, 0, stream>>>(lS_i, occ, out_lookup_f, ws_lookup);
    gather_kernel<<<(T_TABLES * B_BATCH) / 4, 256, 0, stream>>>(
        lS_o, lS_i, ws_lookup, cw, ft, out_pooled);
}